// Round 5
// baseline (762.247 us; speedup 1.0000x reference)
//
#include <hip/hip_runtime.h>

#define Bz 8
#define Nz 1024
#define Dz 1024
#define Hz 16
#define HDz 64
#define DFFz 4096

typedef __attribute__((ext_vector_type(8))) __bf16 bh8;
typedef __attribute__((ext_vector_type(4))) __bf16 bh4;
typedef __attribute__((ext_vector_type(4))) float f4;

#define GLOAD16(gp, lp) __builtin_amdgcn_global_load_lds( \
    (__attribute__((address_space(1))) void*)(gp), \
    (__attribute__((address_space(3))) void*)(lp), 16, 0, 0)

// ---------------- fp32 -> bf16 convert ----------------
__global__ __launch_bounds__(256) void cvt_k(const float* __restrict__ in,
                                             __bf16* __restrict__ out, int n4) {
    int i = blockIdx.x * 256 + threadIdx.x;
    if (i < n4) {
        float4 v = ((const float4*)in)[i];
        bh4 o;
        o[0] = (__bf16)v.x; o[1] = (__bf16)v.y; o[2] = (__bf16)v.z; o[3] = (__bf16)v.w;
        ((bh4*)out)[i] = o;
    }
}

// ---------------- LayerNorm (fp32 in -> bf16 out), one block per row, D=1024 ----------------
__global__ __launch_bounds__(256) void ln_k(const float* __restrict__ x,
                                            const float* __restrict__ g,
                                            const float* __restrict__ bb,
                                            __bf16* __restrict__ out) {
    const int row = blockIdx.x, t = threadIdx.x;
    const float4 v = ((const float4*)(x + (size_t)row * Dz))[t];
    float s = v.x + v.y + v.z + v.w;
    float s2 = v.x * v.x + v.y * v.y + v.z * v.z + v.w * v.w;
#pragma unroll
    for (int off = 32; off > 0; off >>= 1) {
        s += __shfl_down(s, off);
        s2 += __shfl_down(s2, off);
    }
    __shared__ float ps[4], ps2[4];
    if ((t & 63) == 0) { ps[t >> 6] = s; ps2[t >> 6] = s2; }
    __syncthreads();
    float ts = 0.f, ts2 = 0.f;
#pragma unroll
    for (int i = 0; i < 4; i++) { ts += ps[i]; ts2 += ps2[i]; }
    const float mean = ts * (1.f / Dz);
    const float var = ts2 * (1.f / Dz) - mean * mean;
    const float inv = rsqrtf(var + 1e-5f);
    const float4 gv = ((const float4*)g)[t];
    const float4 bv = ((const float4*)bb)[t];
    bh4 o;
    o[0] = (__bf16)((v.x - mean) * inv * gv.x + bv.x);
    o[1] = (__bf16)((v.y - mean) * inv * gv.y + bv.y);
    o[2] = (__bf16)((v.z - mean) * inv * gv.z + bv.z);
    o[3] = (__bf16)((v.w - mean) * inv * gv.w + bv.w);
    *(bh4*)&out[(size_t)row * Dz + t * 4] = o;
}

// ---------------- 256-wide-tile bf16 GEMM, triple-buffered counted-vmcnt pipeline ------------
// C = A[M,K] * W[N,K]^T (+epilogue). BM=256, BK=32, BN in {128,256}. 512 threads = 8 waves
// (2 M-waves x 4 N-waves), per-wave output 128 x BN/4. LDS chunk swizzle: 16B chunk c of
// row r stored at slot c ^ ((r>>1)&3); applied on the global SOURCE address (rule 21),
// read back with the same key -> 2-way (free) bank access on ds_read_b128.
// Pipeline: stage(t+2) || compute(t), then s_waitcnt vmcnt(LPT) lgkmcnt(0) + raw s_barrier.
// vmcnt never drains to 0 in the main loop (T3+T4).
template <int EPI, int BN>
__global__ __launch_bounds__(512, 2) void gemm256(
    const __bf16* __restrict__ A, const __bf16* __restrict__ W,
    const float* __restrict__ bias, void* __restrict__ outp,
    const float* __restrict__ addf, const __bf16* __restrict__ upb,
    int M, int N, int K) {
    constexpr int NB = BN / 64;        // B frags per wave (4 or 2)
    constexpr int ASZ = 256 * 32;      // elements per A K-tile (16KB)
    constexpr int BSZ = BN * 32;       // elements per B K-tile
    constexpr int LPT = 2 + BN / 128;  // gload_lds per thread per K-tile (4 or 3)
    __shared__ __align__(16) __bf16 lsA[3 * ASZ];
    __shared__ __align__(16) __bf16 lsB[3 * BSZ];
    const int t = threadIdx.x;
    const int w = t >> 6, l = t & 63;
    const int lo = l & 15, hi = l >> 4;
    const int wr = w >> 2, wc = w & 3;
    const int brow = blockIdx.y, bcol = blockIdx.x;

    // staging source: row sr (and sr+128), pre-swizzled 16B chunk
    const int sr = t >> 2;
    const int sc = (t & 3) ^ ((sr >> 1) & 3);
    const __bf16* Ag = A + (size_t)(brow * 256 + sr) * K + sc * 8;
    const __bf16* Wg = W + (size_t)(bcol * BN + sr) * K + sc * 8;

    const f4 zf = {0.f, 0.f, 0.f, 0.f};
    f4 acc[8][NB];
#pragma unroll
    for (int m = 0; m < 8; m++)
#pragma unroll
        for (int n = 0; n < NB; n++) acc[m][n] = zf;

    const int sl8 = 8 * (hi ^ ((lo >> 1) & 3));  // swizzled slot (elem offset) for frag reads

#define STAGE(BUF, KT) do { \
        const size_t ko = (size_t)(KT) * 32; \
        GLOAD16(Ag + ko, lsA + (BUF) * ASZ + w * 512); \
        GLOAD16(Ag + (size_t)128 * K + ko, lsA + (BUF) * ASZ + 4096 + w * 512); \
        GLOAD16(Wg + ko, lsB + (BUF) * BSZ + w * 512); \
        if (BN == 256) GLOAD16(Wg + (size_t)128 * K + ko, lsB + (BUF) * BSZ + 4096 + w * 512); \
    } while (0)

#define COMPUTE(BUF) do { \
        const __bf16* la = lsA + (BUF) * ASZ; \
        const __bf16* lb = lsB + (BUF) * BSZ; \
        bh8 af[8], bfv[NB]; \
        _Pragma("unroll") \
        for (int m = 0; m < 8; m++) \
            af[m] = *(const bh8*)&la[(wr * 128 + m * 16 + lo) * 32 + sl8]; \
        _Pragma("unroll") \
        for (int n = 0; n < NB; n++) \
            bfv[n] = *(const bh8*)&lb[(wc * (BN / 4) + n * 16 + lo) * 32 + sl8]; \
        __builtin_amdgcn_s_setprio(1); \
        _Pragma("unroll") \
        for (int m = 0; m < 8; m++) \
            _Pragma("unroll") \
            for (int n = 0; n < NB; n++) \
                acc[m][n] = __builtin_amdgcn_mfma_f32_16x16x32_bf16(af[m], bfv[n], acc[m][n], 0, 0, 0); \
        __builtin_amdgcn_s_setprio(0); \
    } while (0)

    const int nt = K >> 5;  // >= 32 for K=1024
    STAGE(0, 0);
    STAGE(1, 1);
    asm volatile("s_waitcnt vmcnt(%0)" :: "n"(LPT) : "memory");  // tile 0 landed (tile 1 in flight)
    __builtin_amdgcn_s_barrier();
    for (int kt = 0; kt < nt - 2; ++kt) {
        STAGE((kt + 2) % 3, kt + 2);        // overwrites buffer computed 3 steps ago (safe: barrier-ordered)
        COMPUTE(kt % 3);
        // own tile-(kt+1) loads landed; tile-(kt+2) loads stay in flight across the barrier.
        // lgkmcnt(0): this wave's ds_reads complete before the barrier (no sink-past-barrier race).
        asm volatile("s_waitcnt vmcnt(%0) lgkmcnt(0)" :: "n"(LPT) : "memory");
        __builtin_amdgcn_s_barrier();
    }
    COMPUTE((nt - 2) % 3);
    asm volatile("s_waitcnt vmcnt(0) lgkmcnt(0)" ::: "memory");
    __builtin_amdgcn_s_barrier();
    COMPUTE((nt - 1) % 3);
#undef STAGE
#undef COMPUTE

    const int gr0 = brow * 256 + wr * 128;
    const int gc0 = bcol * BN + wc * (BN / 4);
#pragma unroll
    for (int m = 0; m < 8; m++)
#pragma unroll
        for (int n = 0; n < NB; n++) {
            const int col = gc0 + n * 16 + lo;
            const float bv = bias[col];
#pragma unroll
            for (int j = 0; j < 4; j++) {
                const int row = gr0 + m * 16 + hi * 4 + j;
                const size_t idx = (size_t)row * N + col;
                const float v = acc[m][n][j] + bv;
                if (EPI == 0) {
                    ((__bf16*)outp)[idx] = (__bf16)v;
                } else if (EPI == 1 || EPI == 2) {
                    ((float*)outp)[idx] = addf[idx] + v;
                } else {
                    const float u = (float)upb[idx];
                    const float sv = v / (1.f + __expf(-v));
                    ((__bf16*)outp)[idx] = (__bf16)(sv * u);
                }
            }
        }
}

// ---------------- Flash attention with ALiBi (round-4 known-good) ----------------
__global__ __launch_bounds__(256) void attn_k(const __bf16* __restrict__ qkv,
                                              __bf16* __restrict__ out) {
    const int t = threadIdx.x, w = t >> 6, l = t & 63;
    const int qt = blockIdx.x, h = blockIdx.y, b = blockIdx.z;
    const int qbase = qt * 64;
    const int lo = l & 15, hi = l >> 4;
    const float slope = exp2f(-0.5f * (float)(h + 1));

    const size_t base = (size_t)b * Nz * 3072 + h * 64;
    const __bf16* qp = qkv + base;
    const __bf16* kp = qkv + base + 1024;
    const __bf16* vp = qkv + base + 2048;

    __shared__ __align__(16) __bf16 lsK[64 * 64];
    __shared__ __align__(16) __bf16 lsVt[64 * 72];
    __shared__ __align__(16) __bf16 lsP[4 * 16 * 64];

    const int myq = qbase + w * 16 + lo;
    const bh8 qf0 = *(const bh8*)(qp + (size_t)myq * 3072 + hi * 8);
    const bh8 qf1 = *(const bh8*)(qp + (size_t)myq * 3072 + 32 + hi * 8);

    const f4 zf = {0.f, 0.f, 0.f, 0.f};
    float m_run[4], l_run[4];
    f4 oacc[4];
#pragma unroll
    for (int jj = 0; jj < 4; jj++) { m_run[jj] = -1e30f; l_run[jj] = 0.f; }
#pragma unroll
    for (int n = 0; n < 4; n++) oacc[n] = zf;

    const int jr = t >> 2, d0 = (t & 3) * 16;

    for (int j0 = 0; j0 < Nz; j0 += 64) {
        __syncthreads();
        {  // stage K tile, XOR-swizzled rows
            const __bf16* krow = kp + (size_t)(j0 + jr) * 3072 + d0;
            const int sw = (jr & 7) * 8;
            *(bh8*)&lsK[jr * 64 + (d0 ^ sw)] = *(const bh8*)krow;
            *(bh8*)&lsK[jr * 64 + ((d0 + 8) ^ sw)] = *(const bh8*)(krow + 8);
        }
        {  // stage V transposed: lsVt[d][j], padded stride 72
            const int d = t & 63;
            bh8 t0, t1;
#pragma unroll
            for (int jj = 0; jj < 8; jj++) t0[jj] = vp[(size_t)(j0 + w * 16 + jj) * 3072 + d];
#pragma unroll
            for (int jj = 0; jj < 8; jj++) t1[jj] = vp[(size_t)(j0 + w * 16 + 8 + jj) * 3072 + d];
            *(bh8*)&lsVt[d * 72 + w * 16] = t0;
            *(bh8*)&lsVt[d * 72 + w * 16 + 8] = t1;
        }
        __syncthreads();

        float vals[4][4];
#pragma unroll
        for (int c = 0; c < 4; c++) {
            const int krw = c * 16 + lo;
            const int swr = (krw & 7);
            const bh8 kf0 = *(const bh8*)&lsK[krw * 64 + 8 * (hi ^ swr)];
            const bh8 kf1 = *(const bh8*)&lsK[krw * 64 + 8 * ((4 + hi) ^ swr)];
            f4 s = zf;
            s = __builtin_amdgcn_mfma_f32_16x16x32_bf16(qf0, kf0, s, 0, 0, 0);
            s = __builtin_amdgcn_mfma_f32_16x16x32_bf16(qf1, kf1, s, 0, 0, 0);
            const int gj = j0 + c * 16 + lo;
#pragma unroll
            for (int jj = 0; jj < 4; jj++) {
                const int gq = qbase + w * 16 + hi * 4 + jj;
                vals[c][jj] = s[jj] * 0.125f - slope * fabsf((float)(gq - gj));
            }
        }
        float mc[4];
#pragma unroll
        for (int jj = 0; jj < 4; jj++)
            mc[jj] = fmaxf(fmaxf(vals[0][jj], vals[1][jj]), fmaxf(vals[2][jj], vals[3][jj]));
#pragma unroll
        for (int off = 8; off > 0; off >>= 1)
#pragma unroll
            for (int jj = 0; jj < 4; jj++) mc[jj] = fmaxf(mc[jj], __shfl_xor(mc[jj], off));
        float corr[4], psum[4];
#pragma unroll
        for (int jj = 0; jj < 4; jj++) {
            const float mn = fmaxf(m_run[jj], mc[jj]);
            corr[jj] = __expf(m_run[jj] - mn);
            m_run[jj] = mn;
            psum[jj] = 0.f;
        }
#pragma unroll
        for (int c = 0; c < 4; c++)
#pragma unroll
            for (int jj = 0; jj < 4; jj++) {
                const float p = __expf(vals[c][jj] - m_run[jj]);
                vals[c][jj] = p;
                psum[jj] += p;
            }
#pragma unroll
        for (int off = 8; off > 0; off >>= 1)
#pragma unroll
            for (int jj = 0; jj < 4; jj++) psum[jj] += __shfl_xor(psum[jj], off);
#pragma unroll
        for (int jj = 0; jj < 4; jj++) l_run[jj] = l_run[jj] * corr[jj] + psum[jj];
#pragma unroll
        for (int n = 0; n < 4; n++)
#pragma unroll
            for (int jj = 0; jj < 4; jj++) oacc[n][jj] *= corr[jj];

#pragma unroll
        for (int c = 0; c < 4; c++)
#pragma unroll
            for (int jj = 0; jj < 4; jj++) {
                const int q = hi * 4 + jj;
                lsP[w * 1024 + q * 64 + ((c * 16 + lo) ^ ((q & 7) * 8))] = (__bf16)vals[c][jj];
            }

        const int psw = (lo & 7);
        const bh8 pa0 = *(const bh8*)&lsP[w * 1024 + lo * 64 + 8 * (hi ^ psw)];
        const bh8 pa1 = *(const bh8*)&lsP[w * 1024 + lo * 64 + 8 * ((4 + hi) ^ psw)];

#pragma unroll
        for (int n = 0; n < 4; n++) {
            const bh8 vf0 = *(const bh8*)&lsVt[(n * 16 + lo) * 72 + hi * 8];
            const bh8 vf1 = *(const bh8*)&lsVt[(n * 16 + lo) * 72 + 32 + hi * 8];
            oacc[n] = __builtin_amdgcn_mfma_f32_16x16x32_bf16(pa0, vf0, oacc[n], 0, 0, 0);
            oacc[n] = __builtin_amdgcn_mfma_f32_16x16x32_bf16(pa1, vf1, oacc[n], 0, 0, 0);
        }
    }

#pragma unroll
    for (int n = 0; n < 4; n++)
#pragma unroll
        for (int jj = 0; jj < 4; jj++) {
            const int gq = qbase + w * 16 + hi * 4 + jj;
            const int d = n * 16 + lo;
            out[((size_t)b * Nz + gq) * Dz + h * 64 + d] = (__bf16)(oacc[n][jj] / l_run[jj]);
        }
}

extern "C" void kernel_launch(void* const* d_in, const int* in_sizes, int n_in,
                              void* d_out, int out_size, void* d_ws, size_t ws_size,
                              hipStream_t stream) {
    const float* src  = (const float*)d_in[0];
    const float* wqkv = (const float*)d_in[1];
    const float* bqkv = (const float*)d_in[2];
    const float* wo   = (const float*)d_in[3];
    const float* bo   = (const float*)d_in[4];
    const float* g1   = (const float*)d_in[5];
    const float* b1   = (const float*)d_in[6];
    const float* g2   = (const float*)d_in[7];
    const float* b2   = (const float*)d_in[8];
    const float* wg   = (const float*)d_in[9];
    const float* bg   = (const float*)d_in[10];
    const float* wu   = (const float*)d_in[11];
    const float* bu   = (const float*)d_in[12];
    const float* wd   = (const float*)d_in[13];
    const float* bd   = (const float*)d_in[14];
    float* out = (float*)d_out;

    __bf16* wqkv_b = (__bf16*)d_ws;                       // 3072*1024
    __bf16* wo_b   = wqkv_b + (size_t)3072 * 1024;        // 1024*1024
    __bf16* wg_b   = wo_b + (size_t)1024 * 1024;          // 4096*1024
    __bf16* wu_b   = wg_b + (size_t)4096 * 1024;          // 4096*1024
    __bf16* wd_b   = wu_b + (size_t)4096 * 1024;          // 1024*4096
    __bf16* lnbuf  = wd_b + (size_t)1024 * 4096;          // 8192*1024
    __bf16* qkv    = lnbuf + (size_t)8192 * 1024;         // 8192*3072
    __bf16* attno  = qkv + (size_t)8192 * 3072;           // 8192*1024
    float*  x1     = (float*)(attno + (size_t)8192 * 1024);  // 8192*1024 fp32
    __bf16* hb     = qkv;  // reuse dead qkv+attno region: 8192*4096 bf16

    cvt_k<<<3072, 256, 0, stream>>>(wqkv, wqkv_b, 3072 * 1024 / 4);
    cvt_k<<<1024, 256, 0, stream>>>(wo, wo_b, 1024 * 1024 / 4);
    cvt_k<<<4096, 256, 0, stream>>>(wg, wg_b, 4096 * 1024 / 4);
    cvt_k<<<4096, 256, 0, stream>>>(wu, wu_b, 4096 * 1024 / 4);
    cvt_k<<<4096, 256, 0, stream>>>(wd, wd_b, 1024 * 4096 / 4);

    // x = src + attn(LN1(src))
    ln_k<<<8192, 256, 0, stream>>>(src, g1, b1, lnbuf);
    gemm256<0, 128><<<dim3(3072 / 128, 8192 / 256), 512, 0, stream>>>(
        lnbuf, wqkv_b, bqkv, qkv, nullptr, nullptr, 8192, 3072, 1024);
    attn_k<<<dim3(16, 16, 8), 256, 0, stream>>>(qkv, attno);
    gemm256<1, 128><<<dim3(1024 / 128, 8192 / 256), 512, 0, stream>>>(
        attno, wo_b, bo, x1, src, nullptr, 8192, 1024, 1024);

    // x = x + swiglu(LN2(x))
    ln_k<<<8192, 256, 0, stream>>>(x1, g2, b2, lnbuf);
    gemm256<0, 256><<<dim3(4096 / 256, 8192 / 256), 512, 0, stream>>>(
        lnbuf, wu_b, bu, hb, nullptr, nullptr, 8192, 4096, 1024);
    gemm256<3, 256><<<dim3(4096 / 256, 8192 / 256), 512, 0, stream>>>(
        lnbuf, wg_b, bg, hb, nullptr, hb, 8192, 4096, 1024);
    gemm256<2, 128><<<dim3(1024 / 128, 8192 / 256), 512, 0, stream>>>(
        hb, wd_b, bd, out, x1, nullptr, 8192, 1024, 4096);
}

// Round 6
// 744.040 us; speedup vs baseline: 1.0245x; 1.0245x over previous
//
#include <hip/hip_runtime.h>

#define Bz 8
#define Nz 1024
#define Dz 1024
#define Hz 16
#define HDz 64
#define DFFz 4096

typedef __attribute__((ext_vector_type(8))) __bf16 bh8;
typedef __attribute__((ext_vector_type(4))) __bf16 bh4;
typedef __attribute__((ext_vector_type(4))) float f4;

#define GLOAD16(gp, lp) __builtin_amdgcn_global_load_lds( \
    (__attribute__((address_space(1))) void*)(gp), \
    (__attribute__((address_space(3))) void*)(lp), 16, 0, 0)

// ---------------- fp32 -> bf16 convert ----------------
__global__ __launch_bounds__(256) void cvt_k(const float* __restrict__ in,
                                             __bf16* __restrict__ out, int n4) {
    int i = blockIdx.x * 256 + threadIdx.x;
    if (i < n4) {
        float4 v = ((const float4*)in)[i];
        bh4 o;
        o[0] = (__bf16)v.x; o[1] = (__bf16)v.y; o[2] = (__bf16)v.z; o[3] = (__bf16)v.w;
        ((bh4*)out)[i] = o;
    }
}

// ---------------- LayerNorm (fp32 in -> bf16 out), one block per row, D=1024 ----------------
__global__ __launch_bounds__(256) void ln_k(const float* __restrict__ x,
                                            const float* __restrict__ g,
                                            const float* __restrict__ bb,
                                            __bf16* __restrict__ out) {
    const int row = blockIdx.x, t = threadIdx.x;
    const float4 v = ((const float4*)(x + (size_t)row * Dz))[t];
    float s = v.x + v.y + v.z + v.w;
    float s2 = v.x * v.x + v.y * v.y + v.z * v.z + v.w * v.w;
#pragma unroll
    for (int off = 32; off > 0; off >>= 1) {
        s += __shfl_down(s, off);
        s2 += __shfl_down(s2, off);
    }
    __shared__ float ps[4], ps2[4];
    if ((t & 63) == 0) { ps[t >> 6] = s; ps2[t >> 6] = s2; }
    __syncthreads();
    float ts = 0.f, ts2 = 0.f;
#pragma unroll
    for (int i = 0; i < 4; i++) { ts += ps[i]; ts2 += ps2[i]; }
    const float mean = ts * (1.f / Dz);
    const float var = ts2 * (1.f / Dz) - mean * mean;
    const float inv = rsqrtf(var + 1e-5f);
    const float4 gv = ((const float4*)g)[t];
    const float4 bv = ((const float4*)bb)[t];
    bh4 o;
    o[0] = (__bf16)((v.x - mean) * inv * gv.x + bv.x);
    o[1] = (__bf16)((v.y - mean) * inv * gv.y + bv.y);
    o[2] = (__bf16)((v.z - mean) * inv * gv.z + bv.z);
    o[3] = (__bf16)((v.w - mean) * inv * gv.w + bv.w);
    *(bh4*)&out[(size_t)row * Dz + t * 4] = o;
}

// ---------------- 128x128-tile bf16 GEMM, 2-phase double-buffered (round-4 known-good) -------
template <int EPI>
__global__ __launch_bounds__(256) void gemm128(
    const __bf16* __restrict__ A, const __bf16* __restrict__ W,
    const float* __restrict__ bias, void* __restrict__ outp,
    const float* __restrict__ addf, const __bf16* __restrict__ upb,
    int M, int N, int K) {
    __shared__ __align__(16) __bf16 lsA[2 * 128 * 32];
    __shared__ __align__(16) __bf16 lsB[2 * 128 * 32];
    const int t = threadIdx.x;
    const int w = t >> 6, l = t & 63;
    const int brow = blockIdx.y, bcol = blockIdx.x;

    const __bf16* Ag = A + (size_t)(brow * 128 + (t >> 2)) * K + (t & 3) * 8;
    const __bf16* Wg = W + (size_t)(bcol * 128 + (t >> 2)) * K + (t & 3) * 8;

    const f4 zf = {0.f, 0.f, 0.f, 0.f};
    f4 acc[4][4];
#pragma unroll
    for (int m = 0; m < 4; m++)
#pragma unroll
        for (int n = 0; n < 4; n++) acc[m][n] = zf;

    const int lo = l & 15, hi = l >> 4;
    const int rowA = (w >> 1) * 64 + lo;
    const int colB = (w & 1) * 64 + lo;
    const int kk = hi * 8;

#define STAGE(P, KOFF) do { \
        GLOAD16(Ag + (KOFF), lsA + (P) * 4096 + w * 512); \
        GLOAD16(Ag + (size_t)64 * K + (KOFF), lsA + (P) * 4096 + w * 512 + 64 * 32); \
        GLOAD16(Wg + (KOFF), lsB + (P) * 4096 + w * 512); \
        GLOAD16(Wg + (size_t)64 * K + (KOFF), lsB + (P) * 4096 + w * 512 + 64 * 32); \
    } while (0)

#define COMPUTE(P) do { \
        const __bf16* la = lsA + (P) * 4096; \
        const __bf16* lb = lsB + (P) * 4096; \
        bh8 af[4], bfv[4]; \
        _Pragma("unroll") \
        for (int m = 0; m < 4; m++) af[m] = *(const bh8*)&la[(rowA + m * 16) * 32 + kk]; \
        _Pragma("unroll") \
        for (int n = 0; n < 4; n++) bfv[n] = *(const bh8*)&lb[(colB + n * 16) * 32 + kk]; \
        _Pragma("unroll") \
        for (int m = 0; m < 4; m++) \
            _Pragma("unroll") \
            for (int n = 0; n < 4; n++) \
                acc[m][n] = __builtin_amdgcn_mfma_f32_16x16x32_bf16(af[m], bfv[n], acc[m][n], 0, 0, 0); \
    } while (0)

    const int nt = K >> 5;
    int cur = 0;
    STAGE(0, 0);
    __syncthreads();
    for (int kt = 0; kt < nt - 1; ++kt) {
        STAGE(cur ^ 1, (kt + 1) * 32);
        COMPUTE(cur);
        __syncthreads();
        cur ^= 1;
    }
    COMPUTE(cur);
#undef STAGE
#undef COMPUTE

    const int gr0 = brow * 128 + (w >> 1) * 64;
    const int gc0 = bcol * 128 + (w & 1) * 64;
#pragma unroll
    for (int m = 0; m < 4; m++)
#pragma unroll
        for (int n = 0; n < 4; n++) {
            const int col = gc0 + n * 16 + lo;
            const float bv = bias[col];
#pragma unroll
            for (int j = 0; j < 4; j++) {
                const int row = gr0 + m * 16 + hi * 4 + j;
                const size_t idx = (size_t)row * N + col;
                const float v = acc[m][n][j] + bv;
                if (EPI == 0) {
                    ((__bf16*)outp)[idx] = (__bf16)v;
                } else if (EPI == 1 || EPI == 2) {
                    ((float*)outp)[idx] = addf[idx] + v;
                } else {
                    const float u = (float)upb[idx];
                    const float sv = v / (1.f + __expf(-v));
                    ((__bf16*)outp)[idx] = (__bf16)(sv * u);
                }
            }
        }
}

// ---------------- Flash attention with ALiBi, 128 q-rows per block ----------------
// grid (N/128, H, B), 256 threads = 4 waves; wave w owns 32 q-rows = 2 groups of 16,
// processed sequentially per staged K/V tile (halves staging cost per q-row).
// lsK: [64 j][64 d], chunk-XOR swizzled (audited, HW-verified round 4)
// lsVt: [64 d][64+8 j] transposed, padded stride 72 (known-good)
// lsP: per-wave [16 q][64 j], XOR-swizzled; reused by both groups sequentially.
__global__ __launch_bounds__(256) void attn_k(const __bf16* __restrict__ qkv,
                                              __bf16* __restrict__ out) {
    const int t = threadIdx.x, w = t >> 6, l = t & 63;
    const int qt = blockIdx.x, h = blockIdx.y, b = blockIdx.z;
    const int qbase = qt * 128;
    const int lo = l & 15, hi = l >> 4;
    const float slope = exp2f(-0.5f * (float)(h + 1));

    const size_t base = (size_t)b * Nz * 3072 + h * 64;
    const __bf16* qp = qkv + base;
    const __bf16* kp = qkv + base + 1024;
    const __bf16* vp = qkv + base + 2048;

    __shared__ __align__(16) __bf16 lsK[64 * 64];
    __shared__ __align__(16) __bf16 lsVt[64 * 72];
    __shared__ __align__(16) __bf16 lsP[4 * 16 * 64];

    // per-group state (static indexing only)
    bh8 qf[2][2];
    f4 oacc[2][4];
    float m_run[2][4], l_run[2][4];
    const f4 zf = {0.f, 0.f, 0.f, 0.f};
#pragma unroll
    for (int g = 0; g < 2; g++) {
        const int myq = qbase + w * 32 + g * 16 + lo;
        qf[g][0] = *(const bh8*)(qp + (size_t)myq * 3072 + hi * 8);
        qf[g][1] = *(const bh8*)(qp + (size_t)myq * 3072 + 32 + hi * 8);
#pragma unroll
        for (int jj = 0; jj < 4; jj++) { m_run[g][jj] = -1e30f; l_run[g][jj] = 0.f; }
#pragma unroll
        for (int n = 0; n < 4; n++) oacc[g][n] = zf;
    }

    const int jr = t >> 2, d0 = (t & 3) * 16;

    for (int j0 = 0; j0 < Nz; j0 += 64) {
        __syncthreads();
        {  // stage K tile, XOR-swizzled rows
            const __bf16* krow = kp + (size_t)(j0 + jr) * 3072 + d0;
            const int sw = (jr & 7) * 8;
            *(bh8*)&lsK[jr * 64 + (d0 ^ sw)] = *(const bh8*)krow;
            *(bh8*)&lsK[jr * 64 + ((d0 + 8) ^ sw)] = *(const bh8*)(krow + 8);
        }
        {  // stage V transposed: lsVt[d][j], padded stride 72
            const int d = t & 63;
            bh8 t0, t1;
#pragma unroll
            for (int jj = 0; jj < 8; jj++) t0[jj] = vp[(size_t)(j0 + w * 16 + jj) * 3072 + d];
#pragma unroll
            for (int jj = 0; jj < 8; jj++) t1[jj] = vp[(size_t)(j0 + w * 16 + 8 + jj) * 3072 + d];
            *(bh8*)&lsVt[d * 72 + w * 16] = t0;
            *(bh8*)&lsVt[d * 72 + w * 16 + 8] = t1;
        }
        __syncthreads();

#pragma unroll
        for (int g = 0; g < 2; g++) {
            // S = Q K^T over 4 column chunks of 16, + scale + alibi
            float vals[4][4];
#pragma unroll
            for (int c = 0; c < 4; c++) {
                const int krw = c * 16 + lo;
                const int swr = (krw & 7);
                const bh8 kf0 = *(const bh8*)&lsK[krw * 64 + 8 * (hi ^ swr)];
                const bh8 kf1 = *(const bh8*)&lsK[krw * 64 + 8 * ((4 + hi) ^ swr)];
                f4 s = zf;
                s = __builtin_amdgcn_mfma_f32_16x16x32_bf16(qf[g][0], kf0, s, 0, 0, 0);
                s = __builtin_amdgcn_mfma_f32_16x16x32_bf16(qf[g][1], kf1, s, 0, 0, 0);
                const int gj = j0 + c * 16 + lo;
#pragma unroll
                for (int jj = 0; jj < 4; jj++) {
                    const int gq = qbase + w * 32 + g * 16 + hi * 4 + jj;
                    vals[c][jj] = s[jj] * 0.125f - slope * fabsf((float)(gq - gj));
                }
            }
            // online softmax (row = hi*4+jj, spread over 16 lanes of lo)
            float mc[4];
#pragma unroll
            for (int jj = 0; jj < 4; jj++)
                mc[jj] = fmaxf(fmaxf(vals[0][jj], vals[1][jj]), fmaxf(vals[2][jj], vals[3][jj]));
#pragma unroll
            for (int off = 8; off > 0; off >>= 1)
#pragma unroll
                for (int jj = 0; jj < 4; jj++) mc[jj] = fmaxf(mc[jj], __shfl_xor(mc[jj], off));
            float corr[4], psum[4];
#pragma unroll
            for (int jj = 0; jj < 4; jj++) {
                const float mn = fmaxf(m_run[g][jj], mc[jj]);
                corr[jj] = __expf(m_run[g][jj] - mn);
                m_run[g][jj] = mn;
                psum[jj] = 0.f;
            }
#pragma unroll
            for (int c = 0; c < 4; c++)
#pragma unroll
                for (int jj = 0; jj < 4; jj++) {
                    const float p = __expf(vals[c][jj] - m_run[g][jj]);
                    vals[c][jj] = p;
                    psum[jj] += p;
                }
#pragma unroll
            for (int off = 8; off > 0; off >>= 1)
#pragma unroll
                for (int jj = 0; jj < 4; jj++) psum[jj] += __shfl_xor(psum[jj], off);
#pragma unroll
            for (int jj = 0; jj < 4; jj++) l_run[g][jj] = l_run[g][jj] * corr[jj] + psum[jj];
#pragma unroll
            for (int n = 0; n < 4; n++)
#pragma unroll
                for (int jj = 0; jj < 4; jj++) oacc[g][n][jj] *= corr[jj];

            // P -> LDS (wave-private, XOR-swizzled); same region reused per group (same-wave
            // write->read->write ordering enforced by DS pipe + compiler lgkmcnt)
#pragma unroll
            for (int c = 0; c < 4; c++)
#pragma unroll
                for (int jj = 0; jj < 4; jj++) {
                    const int q = hi * 4 + jj;
                    lsP[w * 1024 + q * 64 + ((c * 16 + lo) ^ ((q & 7) * 8))] = (__bf16)vals[c][jj];
                }

            const int psw = (lo & 7);
            const bh8 pa0 = *(const bh8*)&lsP[w * 1024 + lo * 64 + 8 * (hi ^ psw)];
            const bh8 pa1 = *(const bh8*)&lsP[w * 1024 + lo * 64 + 8 * ((4 + hi) ^ psw)];

#pragma unroll
            for (int n = 0; n < 4; n++) {
                const bh8 vf0 = *(const bh8*)&lsVt[(n * 16 + lo) * 72 + hi * 8];
                const bh8 vf1 = *(const bh8*)&lsVt[(n * 16 + lo) * 72 + 32 + hi * 8];
                oacc[g][n] = __builtin_amdgcn_mfma_f32_16x16x32_bf16(pa0, vf0, oacc[g][n], 0, 0, 0);
                oacc[g][n] = __builtin_amdgcn_mfma_f32_16x16x32_bf16(pa1, vf1, oacc[g][n], 0, 0, 0);
            }
        }
    }

#pragma unroll
    for (int g = 0; g < 2; g++)
#pragma unroll
        for (int n = 0; n < 4; n++)
#pragma unroll
            for (int jj = 0; jj < 4; jj++) {
                const int gq = qbase + w * 32 + g * 16 + hi * 4 + jj;
                const int d = n * 16 + lo;
                out[((size_t)b * Nz + gq) * Dz + h * 64 + d] =
                    (__bf16)(oacc[g][n][jj] / l_run[g][jj]);
            }
}

extern "C" void kernel_launch(void* const* d_in, const int* in_sizes, int n_in,
                              void* d_out, int out_size, void* d_ws, size_t ws_size,
                              hipStream_t stream) {
    const float* src  = (const float*)d_in[0];
    const float* wqkv = (const float*)d_in[1];
    const float* bqkv = (const float*)d_in[2];
    const float* wo   = (const float*)d_in[3];
    const float* bo   = (const float*)d_in[4];
    const float* g1   = (const float*)d_in[5];
    const float* b1   = (const float*)d_in[6];
    const float* g2   = (const float*)d_in[7];
    const float* b2   = (const float*)d_in[8];
    const float* wg   = (const float*)d_in[9];
    const float* bg   = (const float*)d_in[10];
    const float* wu   = (const float*)d_in[11];
    const float* bu   = (const float*)d_in[12];
    const float* wd   = (const float*)d_in[13];
    const float* bd   = (const float*)d_in[14];
    float* out = (float*)d_out;

    __bf16* wqkv_b = (__bf16*)d_ws;                       // 3072*1024
    __bf16* wo_b   = wqkv_b + (size_t)3072 * 1024;        // 1024*1024
    __bf16* wg_b   = wo_b + (size_t)1024 * 1024;          // 4096*1024
    __bf16* wu_b   = wg_b + (size_t)4096 * 1024;          // 4096*1024
    __bf16* wd_b   = wu_b + (size_t)4096 * 1024;          // 1024*4096
    __bf16* lnbuf  = wd_b + (size_t)1024 * 4096;          // 8192*1024
    __bf16* qkv    = lnbuf + (size_t)8192 * 1024;         // 8192*3072
    __bf16* attno  = qkv + (size_t)8192 * 3072;           // 8192*1024
    float*  x1     = (float*)(attno + (size_t)8192 * 1024);  // 8192*1024 fp32
    __bf16* hb     = qkv;  // reuse dead qkv+attno region: 8192*4096 bf16

    cvt_k<<<3072, 256, 0, stream>>>(wqkv, wqkv_b, 3072 * 1024 / 4);
    cvt_k<<<1024, 256, 0, stream>>>(wo, wo_b, 1024 * 1024 / 4);
    cvt_k<<<4096, 256, 0, stream>>>(wg, wg_b, 4096 * 1024 / 4);
    cvt_k<<<4096, 256, 0, stream>>>(wu, wu_b, 4096 * 1024 / 4);
    cvt_k<<<4096, 256, 0, stream>>>(wd, wd_b, 1024 * 4096 / 4);

    // x = src + attn(LN1(src))
    ln_k<<<8192, 256, 0, stream>>>(src, g1, b1, lnbuf);
    gemm128<0><<<dim3(3072 / 128, 8192 / 128), 256, 0, stream>>>(
        lnbuf, wqkv_b, bqkv, qkv, nullptr, nullptr, 8192, 3072, 1024);
    attn_k<<<dim3(8, 16, 8), 256, 0, stream>>>(qkv, attno);
    gemm128<1><<<dim3(1024 / 128, 8192 / 128), 256, 0, stream>>>(
        attno, wo_b, bo, x1, src, nullptr, 8192, 1024, 1024);

    // x = x + swiglu(LN2(x))
    ln_k<<<8192, 256, 0, stream>>>(x1, g2, b2, lnbuf);
    gemm128<0><<<dim3(4096 / 128, 8192 / 128), 256, 0, stream>>>(
        lnbuf, wu_b, bu, hb, nullptr, nullptr, 8192, 4096, 1024);
    gemm128<3><<<dim3(4096 / 128, 8192 / 128), 256, 0, stream>>>(
        lnbuf, wg_b, bg, hb, nullptr, hb, 8192, 4096, 1024);
    gemm128<2><<<dim3(1024 / 128, 8192 / 128), 256, 0, stream>>>(
        hb, wd_b, bd, out, x1, nullptr, 8192, 1024, 4096);
}